// Round 2
// baseline (602.722 us; speedup 1.0000x reference)
//
#include <hip/hip_runtime.h>
#include <hip/hip_bf16.h>

typedef __attribute__((ext_vector_type(8))) short bf16x8;
typedef __attribute__((ext_vector_type(4))) float f32x4;

#define N_OUT 65536
#define CIN   256
#define COUT  512
#define BM    128
#define BK    64
#define NKS   32    // 2048 / 64 K-steps

struct StageRegs { f32x4 v0, v1, v2, v3; };   // 16 f32 = one (row, 16-k) chunk

__device__ __forceinline__ unsigned short f2bf(float f) {
  union { __hip_bfloat16 h; unsigned short u; } c;
  c.h = __float2bfloat16(f);
  return c.u;
}

// --- weight prep: W[k][n] f32 (row-major) -> Wt tiled bf16:
//     Wt[kb*16384 + n*32 + kk] = bf16(W[kb*32+kk][n]),  kb in [0,64), n in [0,512), kk in [0,32)
__global__ void wprep_kernel(const float* __restrict__ W, unsigned short* __restrict__ Wt) {
  int idx = blockIdx.x * blockDim.x + threadIdx.x;
  if (idx >= 64 * 4 * COUT) return;
  int n  = idx & (COUT - 1);
  int s  = (idx >> 9) & 3;
  int kb = idx >> 11;
  unsigned short tmp[8];
#pragma unroll
  for (int w = 0; w < 8; ++w)
    tmp[w] = f2bf(W[(size_t)(kb * 32 + s * 8 + w) * COUT + n]);
  *reinterpret_cast<bf16x8*>(Wt + ((size_t)kb * 16384 + n * 32 + s * 8)) =
      *reinterpret_cast<bf16x8*>(tmp);
}

// --- main GEMM: out_raw = gather(data,neigh) @ Wt   (+ per-block column partials)
__global__ __launch_bounds__(512, 2) void gemm_kernel(
    const float* __restrict__ data,
    const int*   __restrict__ neigh,
    const unsigned short* __restrict__ Wt,
    float* __restrict__ out,
    float* __restrict__ psum,
    float* __restrict__ psq)
{
  __shared__ union {
    unsigned short as[2][BM * BK];   // 2 x 16 KB, XOR-swizzled 16B chunks
    float st[4][COUT];
  } sm;

  const int tid = threadIdx.x;
  const int l   = tid & 63;
  const int w   = tid >> 6;
  const int wr  = w >> 2;
  const int wc  = w & 3;
  const int lg  = l >> 4;
  const int lm  = l & 15;
  const int m0  = blockIdx.x * BM;

  const int arow = tid >> 2;     // 0..127 : staged row
  const int aqc  = tid & 3;      // 16-float chunk within the 64-k step
  const int r7   = arow & 7;

  f32x4 acc[4][8];
#pragma unroll
  for (int i = 0; i < 4; ++i)
#pragma unroll
    for (int j = 0; j < 8; ++j) acc[i][j] = (f32x4){0.f, 0.f, 0.f, 0.f};

  bf16x8 af[4], bfC[8], bfN[8];
  StageRegs stA, stB;

#define STAGE_ISSUE(S, nb, kloc) do { \
    const f32x4* p_ = reinterpret_cast<const f32x4*>(data + (size_t)(nb) * CIN + (kloc) + aqc * 16); \
    S.v0 = p_[0]; S.v1 = p_[1]; S.v2 = p_[2]; S.v3 = p_[3]; \
  } while (0)

#define STAGE_WRITE(S, buf) do { \
    unsigned short u_[16]; \
    u_[0]=f2bf(S.v0.x);  u_[1]=f2bf(S.v0.y);  u_[2]=f2bf(S.v0.z);  u_[3]=f2bf(S.v0.w); \
    u_[4]=f2bf(S.v1.x);  u_[5]=f2bf(S.v1.y);  u_[6]=f2bf(S.v1.z);  u_[7]=f2bf(S.v1.w); \
    u_[8]=f2bf(S.v2.x);  u_[9]=f2bf(S.v2.y);  u_[10]=f2bf(S.v2.z); u_[11]=f2bf(S.v2.w); \
    u_[12]=f2bf(S.v3.x); u_[13]=f2bf(S.v3.y); u_[14]=f2bf(S.v3.z); u_[15]=f2bf(S.v3.w); \
    *reinterpret_cast<bf16x8*>(&sm.as[buf][arow * 64 + (((aqc * 2)     ^ r7) << 3)]) = *reinterpret_cast<bf16x8*>(u_); \
    *reinterpret_cast<bf16x8*>(&sm.as[buf][arow * 64 + (((aqc * 2 + 1) ^ r7) << 3)]) = *reinterpret_cast<bf16x8*>(u_ + 8); \
  } while (0)

#define LOAD_B(kb, bf) do { \
    const unsigned short* wt_ = Wt + (size_t)(kb) * 16384 + wc * 4096 + lm * 32 + lg * 8; \
    _Pragma("unroll") \
    for (int ni_ = 0; ni_ < 8; ++ni_) bf[ni_] = *reinterpret_cast<const bf16x8*>(wt_ + ni_ * 512); \
  } while (0)

#define LOAD_AF(buf, h) do { \
    _Pragma("unroll") \
    for (int mi_ = 0; mi_ < 4; ++mi_) { \
      int row_ = wr * 64 + mi_ * 16 + lm; \
      af[mi_] = *reinterpret_cast<const bf16x8*>( \
          &sm.as[buf][row_ * 64 + (((((h) * 4) + lg) ^ (row_ & 7)) << 3)]); \
    } \
  } while (0)

#define DO_MFMA(bf) do { \
    _Pragma("unroll") \
    for (int mi_ = 0; mi_ < 4; ++mi_) \
      _Pragma("unroll") \
      for (int ni_ = 0; ni_ < 8; ++ni_) \
        acc[mi_][ni_] = __builtin_amdgcn_mfma_f32_16x16x32_bf16(af[mi_], bf[ni_], acc[mi_][ni_], 0, 0, 0); \
  } while (0)

#define SOFT_BARRIER() do { \
    asm volatile("s_waitcnt lgkmcnt(0)" ::: "memory"); \
    __builtin_amdgcn_s_barrier(); \
  } while (0)

  // ---- prologue: children 0/1 hoisted; steps 0 and 1 staged
  const size_t nbase = (size_t)(m0 + arow) * 8;
  int nb_cur = neigh[nbase + 0];
  int nb_nxt = neigh[nbase + 1];
  STAGE_ISSUE(stB, nb_cur, 0);     // step 0
  STAGE_ISSUE(stA, nb_cur, 64);    // step 1
  LOAD_B(0, bfC);                  // B for step 0, half 0
  STAGE_WRITE(stB, 0);             // counted vmcnt wait on stB only
  SOFT_BARRIER();

  // ---- main loop: 8 children x 4 steps of BK=64 (k-halves via kb32 = 2*step)
  for (int c = 0; c < 8; ++c) {
#pragma unroll
    for (int j = 0; j < 4; ++j) {
      const int kb = (c * 4 + j) * 2;
      // 1. issue staging loads for step i+2 (register set freed last iter)
      if (j == 0)      STAGE_ISSUE(stB, nb_cur, 128);
      else if (j == 1) STAGE_ISSUE(stA, nb_cur, 192);
      else if (j == 2) { if (c < 7) STAGE_ISSUE(stB, nb_nxt, 0);  }
      else             { if (c < 7) STAGE_ISSUE(stA, nb_nxt, 64); }
      // 2. B for half 1 of this step
      LOAD_B(kb + 1, bfN);
      // 3. compute half 0
      LOAD_AF(j & 1, 0);
      DO_MFMA(bfC);
      // 4. B for half 0 of next step
      if (j < 3 || c < 7) LOAD_B(kb + 2, bfC);
      // 5. compute half 1
      LOAD_AF(j & 1, 1);
      DO_MFMA(bfN);
      // 6. convert+write step i+1 into the other LDS buffer; barrier (NO vmcnt drain)
      if (j < 3 || c < 7) {
        if ((j & 1) == 0) STAGE_WRITE(stA, ((j + 1) & 1));
        else              STAGE_WRITE(stB, ((j + 1) & 1));
        SOFT_BARRIER();
      }
    }
    nb_cur = nb_nxt;
    nb_nxt = neigh[nbase + (c + 2 <= 7 ? c + 2 : 7)];
  }

  // ---- epilogue 1: raw out (C layout: col = lane&15, row = (lane>>4)*4 + reg)
#pragma unroll
  for (int mi = 0; mi < 4; ++mi) {
#pragma unroll
    for (int r = 0; r < 4; ++r) {
      size_t row = (size_t)(m0 + wr * 64 + mi * 16 + lg * 4 + r);
      float* op = out + row * COUT + wc * 128 + lm;
#pragma unroll
      for (int ni = 0; ni < 8; ++ni) op[ni * 16] = acc[mi][ni][r];
    }
  }

  // ---- epilogue 2: deterministic per-block column sums/sumsq
  __syncthreads();   // all sm.as reads done before st overlay is written
#pragma unroll
  for (int ni = 0; ni < 8; ++ni) {
    float s1 = 0.f, s2 = 0.f;
#pragma unroll
    for (int mi = 0; mi < 4; ++mi)
#pragma unroll
      for (int r = 0; r < 4; ++r) { float v = acc[mi][ni][r]; s1 += v; s2 += v * v; }
    s1 += __shfl_xor(s1, 16, 64); s1 += __shfl_xor(s1, 32, 64);
    s2 += __shfl_xor(s2, 16, 64); s2 += __shfl_xor(s2, 32, 64);
    if (l < 16) {
      sm.st[wr][wc * 128 + ni * 16 + l]     = s1;
      sm.st[2 + wr][wc * 128 + ni * 16 + l] = s2;
    }
  }
  __syncthreads();
  {
    float S = sm.st[0][tid] + sm.st[1][tid];
    float Q = sm.st[2][tid] + sm.st[3][tid];
    psum[(size_t)blockIdx.x * COUT + tid] = S;
    psq [(size_t)blockIdx.x * COUT + tid] = Q;
  }
#undef STAGE_ISSUE
#undef STAGE_WRITE
#undef LOAD_B
#undef LOAD_AF
#undef DO_MFMA
#undef SOFT_BARRIER
}

// --- stats reduction, stage 1: 512 -> 64 partials per column
__global__ void reduce1_kernel(const float* __restrict__ psum, const float* __restrict__ psq,
                               float* __restrict__ p2) {
  int c = threadIdx.x, b = blockIdx.x;
  float s = 0.f, q = 0.f;
#pragma unroll
  for (int j = 0; j < 8; ++j) {
    s += psum[(size_t)(b * 8 + j) * COUT + c];
    q += psq [(size_t)(b * 8 + j) * COUT + c];
  }
  p2[b * 1024 + c] = s;
  p2[b * 1024 + 512 + c] = q;
}

// --- stats reduction, stage 2: mean/var -> per-column scale/shift
__global__ void reduce2_kernel(const float* __restrict__ p2,
                               const float* __restrict__ gamma,
                               const float* __restrict__ beta,
                               float* __restrict__ scsh) {
  int c = threadIdx.x;
  float s = 0.f, q = 0.f;
  for (int b = 0; b < 64; ++b) { s += p2[b * 1024 + c]; q += p2[b * 1024 + 512 + c]; }
  float mean = s * (1.f / 65536.f);
  float var  = q * (1.f / 65536.f) - mean * mean;
  float rs   = rsqrtf(var + 1e-5f);
  float sc   = gamma[c] * rs;
  scsh[c] = sc;
  scsh[COUT + c] = beta[c] - mean * sc;   // conv bias cancels in BN
}

// --- apply BN in-place
__global__ void bn_kernel(float* __restrict__ out, const float* __restrict__ scsh) {
  __shared__ float sc[COUT], sh[COUT];
  int t = threadIdx.x;
  sc[t] = scsh[t];
  sh[t] = scsh[COUT + t];
  __syncthreads();
  f32x4* o4 = reinterpret_cast<f32x4*>(out);
  const size_t total  = (size_t)N_OUT * COUT / 4;
  const size_t stride = (size_t)gridDim.x * blockDim.x;
  for (size_t i = (size_t)blockIdx.x * blockDim.x + t; i < total; i += stride) {
    f32x4 v = o4[i];
    int c = ((int)(i & 127)) * 4;
    v.x = v.x * sc[c]     + sh[c];
    v.y = v.y * sc[c + 1] + sh[c + 1];
    v.z = v.z * sc[c + 2] + sh[c + 2];
    v.w = v.w * sc[c + 3] + sh[c + 3];
    o4[i] = v;
  }
}

extern "C" void kernel_launch(void* const* d_in, const int* in_sizes, int n_in,
                              void* d_out, int out_size, void* d_ws, size_t ws_size,
                              hipStream_t stream) {
  const float* data   = (const float*)d_in[0];
  const float* weight = (const float*)d_in[1];
  const float* gamma  = (const float*)d_in[3];
  const float* beta   = (const float*)d_in[4];
  const int*   neigh  = (const int*)d_in[5];
  float* out = (float*)d_out;

  char* ws = (char*)d_ws;
  unsigned short* Wt = (unsigned short*)ws;                        // 2 MB
  float* psum = (float*)(ws + (2u << 20));                         // 1 MB
  float* psq  = (float*)(ws + (3u << 20));                         // 1 MB
  float* p2   = (float*)(ws + (4u << 20));                         // 256 KB
  float* scsh = (float*)(ws + (4u << 20) + (256u << 10));          // 4 KB

  wprep_kernel<<<512, 256, 0, stream>>>(weight, Wt);
  gemm_kernel<<<N_OUT / BM, 512, 0, stream>>>(data, neigh, Wt, out, psum, psq);
  reduce1_kernel<<<64, 512, 0, stream>>>(psum, psq, p2);
  reduce2_kernel<<<1, 512, 0, stream>>>(p2, gamma, beta, scsh);
  bn_kernel<<<2048, 512, 0, stream>>>(out, scsh);
}

// Round 3
// 273.635 us; speedup vs baseline: 2.2026x; 2.2026x over previous
//
#include <hip/hip_runtime.h>
#include <hip/hip_bf16.h>

typedef __attribute__((ext_vector_type(8))) short bf16x8;
typedef __attribute__((ext_vector_type(4))) float f32x4;

#define N_OUT 65536
#define CIN   256
#define COUT  512
#define BM    128
#define BK    64
#define NKS   32    // 2048 / 64 K-steps

__device__ __forceinline__ unsigned short f2bf(float f) {
  union { __hip_bfloat16 h; unsigned short u; } c;
  c.h = __float2bfloat16(f);
  return c.u;
}

__device__ __forceinline__ bf16x8 pack8(f32x4 a, f32x4 b) {
  unsigned short u[8];
  u[0] = f2bf(a.x); u[1] = f2bf(a.y); u[2] = f2bf(a.z); u[3] = f2bf(a.w);
  u[4] = f2bf(b.x); u[5] = f2bf(b.y); u[6] = f2bf(b.z); u[7] = f2bf(b.w);
  return *reinterpret_cast<bf16x8*>(u);
}

// async global(fp32, per-lane addr) -> LDS(linear, base + lane*16B)
__device__ __forceinline__ void gload_lds16(const float* g, float* l) {
  __builtin_amdgcn_global_load_lds(
      (const __attribute__((address_space(1))) void*)g,
      (__attribute__((address_space(3))) void*)l, 16, 0, 0);
}

// --- weight prep: W[k][n] f32 -> Wt tiled bf16: Wt[kb][n][kk], kb<64, kk<32
__global__ void wprep_kernel(const float* __restrict__ W, unsigned short* __restrict__ Wt) {
  int idx = blockIdx.x * blockDim.x + threadIdx.x;
  if (idx >= 64 * 4 * COUT) return;
  int n  = idx & (COUT - 1);
  int s  = (idx >> 9) & 3;
  int kb = idx >> 11;
  unsigned short tmp[8];
#pragma unroll
  for (int w = 0; w < 8; ++w)
    tmp[w] = f2bf(W[(size_t)(kb * 32 + s * 8 + w) * COUT + n]);
  *reinterpret_cast<bf16x8*>(Wt + ((size_t)kb * 16384 + n * 32 + s * 8)) =
      *reinterpret_cast<bf16x8*>(tmp);
}

// --- main GEMM: out_raw = gather(data,neigh) @ Wt   (+ per-block column partials)
__global__ __launch_bounds__(512, 2) void gemm_kernel(
    const float* __restrict__ data,
    const int*   __restrict__ neigh,
    const unsigned short* __restrict__ Wt,
    float* __restrict__ out,
    float* __restrict__ psum,
    float* __restrict__ psq)
{
  // A ring: fp32, [3 bufs][128 rows][64 k], rows 256B; 16B chunks XOR-swizzled
  // via pre-swizzled GLOBAL source (rule 21): logical chunk c lives at slot c^(row&15).
  __shared__ union {
    float as[3][BM * BK];      // 3 x 32 KB
    float st[4][COUT];         // stats overlay (used after final barrier)
  } sm;
  __shared__ unsigned int offs[BM * 8];   // per-row, per-child float offset into data

  const int tid = threadIdx.x;
  const int l   = tid & 63;
  const int w   = tid >> 6;
  const int wr  = w >> 2;
  const int wc  = w & 3;
  const int lg  = l >> 4;
  const int lm  = l & 15;
  const int m0  = blockIdx.x * BM;

  f32x4 acc[4][8];
#pragma unroll
  for (int i = 0; i < 4; ++i)
#pragma unroll
    for (int j = 0; j < 8; ++j) acc[i][j] = (f32x4){0.f, 0.f, 0.f, 0.f};

  bf16x8 af[4], bfC[8], bfN[8];

  // ---- neigh -> LDS offset table (1024 entries; lgkm path, not vmcnt)
  for (int e = tid; e < BM * 8; e += 512)
    offs[e] = ((unsigned)neigh[(size_t)m0 * 8 + e]) << 8;   // * 256 floats
  __syncthreads();

  // issue one wave-instr per j: 64 lanes x 16B = 1KB = 4 rows; lane l -> row
  // w*16 + j*4 + (l>>4), slot l&15; source supplies logical chunk (l&15)^(row&15).
#define AISSUE(t_, buf_) do { \
    const int cn_ = (t_) >> 2; \
    const int k0_ = ((t_) & 3) * 64; \
    _Pragma("unroll") \
    for (int j_ = 0; j_ < 4; ++j_) { \
      int rg_ = j_ * 4 + (l >> 4); \
      unsigned off_ = offs[(w * 16 + rg_) * 8 + cn_]; \
      const float* src_ = data + off_ + k0_ + (((l & 15) ^ rg_) << 2); \
      float* dst_ = &sm.as[buf_][(w * 16 + j_ * 4) * BK]; \
      gload_lds16(src_, dst_); \
    } \
  } while (0)

#define LOAD_B(kb, bf) do { \
    const unsigned short* wt_ = Wt + (size_t)(kb) * 16384 + wc * 4096 + lm * 32 + lg * 8; \
    _Pragma("unroll") \
    for (int ni_ = 0; ni_ < 8; ++ni_) bf[ni_] = *reinterpret_cast<const bf16x8*>(wt_ + ni_ * 512); \
  } while (0)

#define LOAD_AF(buf_, h_) do { \
    _Pragma("unroll") \
    for (int mi_ = 0; mi_ < 4; ++mi_) { \
      int R_ = wr * 64 + mi_ * 16 + lm; \
      const f32x4* b_ = reinterpret_cast<const f32x4*>(&sm.as[buf_][R_ * BK]); \
      int c0_ = (h_) * 8 + lg * 2; \
      f32x4 x0_ = b_[c0_ ^ (R_ & 15)]; \
      f32x4 x1_ = b_[(c0_ + 1) ^ (R_ & 15)]; \
      af[mi_] = pack8(x0_, x1_); \
    } \
  } while (0)

#define DO_MFMA(bf) do { \
    _Pragma("unroll") \
    for (int mi_ = 0; mi_ < 4; ++mi_) \
      _Pragma("unroll") \
      for (int ni_ = 0; ni_ < 8; ++ni_) \
        acc[mi_][ni_] = __builtin_amdgcn_mfma_f32_16x16x32_bf16(af[mi_], bf[ni_], acc[mi_][ni_], 0, 0, 0); \
  } while (0)

  // ---- prologue: A for steps 0,1 in flight; B half0 of step 0
  AISSUE(0, 0);
  AISSUE(1, 1);
  LOAD_B(0, bfC);

  int bufc = 0;   // buffer of step t
  int bufp = 2;   // buffer of step t+2
#pragma unroll 1
  for (int t = 0; t < NKS; ++t) {
    // (a) prefetch A(t+2) into the buffer last read at step t-1
    if (t + 2 < NKS) AISSUE(t + 2, bufp);
    // (b) B half1 of step t
    LOAD_B(2 * t + 1, bfN);
    // (c) counted wait: everything older than the newest 24 vmem ops is done
    //     => A(t) landed in LDS (>=24 ops issued after it, incl. t=0 exactly 24).
    //     Never drains A(t+1)/A(t+2)/B(t) -- the pipeline stays filled.
    asm volatile("s_waitcnt vmcnt(24)" ::: "memory");
    __builtin_amdgcn_s_barrier();
    // (e) compute step t; B half0 of t+1 issued between halves
    LOAD_AF(bufc, 0);
    DO_MFMA(bfC);
    if (t + 1 < NKS) LOAD_B(2 * t + 2, bfC);
    LOAD_AF(bufc, 1);
    DO_MFMA(bfN);
    // (f) WAR fence: next iter's AISSUE overwrites the buffer just read
    __builtin_amdgcn_s_barrier();
    bufc = (bufc == 2) ? 0 : bufc + 1;
    bufp = (bufp == 2) ? 0 : bufp + 1;
  }

  // ---- epilogue 1: raw out (C layout: col = lane&15, row = (lane>>4)*4 + reg)
#pragma unroll
  for (int mi = 0; mi < 4; ++mi) {
#pragma unroll
    for (int r = 0; r < 4; ++r) {
      size_t row = (size_t)(m0 + wr * 64 + mi * 16 + lg * 4 + r);
      float* op = out + row * COUT + wc * 128 + lm;
#pragma unroll
      for (int ni = 0; ni < 8; ++ni) op[ni * 16] = acc[mi][ni][r];
    }
  }

  // ---- epilogue 2: deterministic per-block column sums/sumsq
  __syncthreads();   // drain + all LDS reads done before st overlay
#pragma unroll
  for (int ni = 0; ni < 8; ++ni) {
    float s1 = 0.f, s2 = 0.f;
#pragma unroll
    for (int mi = 0; mi < 4; ++mi)
#pragma unroll
      for (int r = 0; r < 4; ++r) { float v = acc[mi][ni][r]; s1 += v; s2 += v * v; }
    s1 += __shfl_xor(s1, 16, 64); s1 += __shfl_xor(s1, 32, 64);
    s2 += __shfl_xor(s2, 16, 64); s2 += __shfl_xor(s2, 32, 64);
    if (l < 16) {
      sm.st[wr][wc * 128 + ni * 16 + l]     = s1;
      sm.st[2 + wr][wc * 128 + ni * 16 + l] = s2;
    }
  }
  __syncthreads();
  {
    float S = sm.st[0][tid] + sm.st[1][tid];
    float Q = sm.st[2][tid] + sm.st[3][tid];
    psum[(size_t)blockIdx.x * COUT + tid] = S;
    psq [(size_t)blockIdx.x * COUT + tid] = Q;
  }
#undef AISSUE
#undef LOAD_B
#undef LOAD_AF
#undef DO_MFMA
}

// --- stats reduction, stage 1: 512 -> 64 partials per column
__global__ void reduce1_kernel(const float* __restrict__ psum, const float* __restrict__ psq,
                               float* __restrict__ p2) {
  int c = threadIdx.x, b = blockIdx.x;
  float s = 0.f, q = 0.f;
#pragma unroll
  for (int j = 0; j < 8; ++j) {
    s += psum[(size_t)(b * 8 + j) * COUT + c];
    q += psq [(size_t)(b * 8 + j) * COUT + c];
  }
  p2[b * 1024 + c] = s;
  p2[b * 1024 + 512 + c] = q;
}

// --- stats reduction, stage 2: mean/var -> per-column scale/shift
__global__ void reduce2_kernel(const float* __restrict__ p2,
                               const float* __restrict__ gamma,
                               const float* __restrict__ beta,
                               float* __restrict__ scsh) {
  int c = threadIdx.x;
  float s = 0.f, q = 0.f;
  for (int b = 0; b < 64; ++b) { s += p2[b * 1024 + c]; q += p2[b * 1024 + 512 + c]; }
  float mean = s * (1.f / 65536.f);
  float var  = q * (1.f / 65536.f) - mean * mean;
  float rs   = rsqrtf(var + 1e-5f);
  float sc   = gamma[c] * rs;
  scsh[c] = sc;
  scsh[COUT + c] = beta[c] - mean * sc;   // conv bias cancels in BN
}

// --- apply BN in-place
__global__ void bn_kernel(float* __restrict__ out, const float* __restrict__ scsh) {
  __shared__ float sc[COUT], sh[COUT];
  int t = threadIdx.x;
  sc[t] = scsh[t];
  sh[t] = scsh[COUT + t];
  __syncthreads();
  f32x4* o4 = reinterpret_cast<f32x4*>(out);
  const size_t total  = (size_t)N_OUT * COUT / 4;
  const size_t stride = (size_t)gridDim.x * blockDim.x;
  for (size_t i = (size_t)blockIdx.x * blockDim.x + t; i < total; i += stride) {
    f32x4 v = o4[i];
    int c = ((int)(i & 127)) * 4;
    v.x = v.x * sc[c]     + sh[c];
    v.y = v.y * sc[c + 1] + sh[c + 1];
    v.z = v.z * sc[c + 2] + sh[c + 2];
    v.w = v.w * sc[c + 3] + sh[c + 3];
    o4[i] = v;
  }
}

extern "C" void kernel_launch(void* const* d_in, const int* in_sizes, int n_in,
                              void* d_out, int out_size, void* d_ws, size_t ws_size,
                              hipStream_t stream) {
  const float* data   = (const float*)d_in[0];
  const float* weight = (const float*)d_in[1];
  const float* gamma  = (const float*)d_in[3];
  const float* beta   = (const float*)d_in[4];
  const int*   neigh  = (const int*)d_in[5];
  float* out = (float*)d_out;

  char* ws = (char*)d_ws;
  unsigned short* Wt = (unsigned short*)ws;                        // 2 MB
  float* psum = (float*)(ws + (2u << 20));                         // 1 MB
  float* psq  = (float*)(ws + (3u << 20));                         // 1 MB
  float* p2   = (float*)(ws + (4u << 20));                         // 256 KB
  float* scsh = (float*)(ws + (4u << 20) + (256u << 10));          // 4 KB

  wprep_kernel<<<512, 256, 0, stream>>>(weight, Wt);
  gemm_kernel<<<N_OUT / BM, 512, 0, stream>>>(data, neigh, Wt, out, psum, psq);
  reduce1_kernel<<<64, 512, 0, stream>>>(psum, psq, p2);
  reduce2_kernel<<<1, 512, 0, stream>>>(p2, gamma, beta, scsh);
  bn_kernel<<<2048, 512, 0, stream>>>(out, scsh);
}